// Round 2
// baseline (549.023 us; speedup 1.0000x reference)
//
#include <hip/hip_runtime.h>
#include <cstdint>
#include <cstddef>

// Problem constants
#define N_TOK 4096     // B*T tokens
#define DM    1024     // d_model
#define DH    2048     // d_hidden
#define NE    8        // experts
#define NSLOT 8192     // total routed slots = N_TOK * top_k

typedef short bf16x8_t __attribute__((ext_vector_type(8)));  // 8 bf16 (4 VGPRs)
typedef float f32x4    __attribute__((ext_vector_type(4)));
typedef unsigned short u16x8 __attribute__((ext_vector_type(8)));

__device__ __forceinline__ unsigned short f2bf(float f) {
  union { float f; unsigned int u; } v; v.f = f;
  unsigned int u = v.u;
  u += 0x7fffu + ((u >> 16) & 1u);   // RNE
  return (unsigned short)(u >> 16);
}

__device__ __forceinline__ float bf2f(unsigned short h) {
  union { unsigned int u; float f; } v; v.u = ((unsigned int)h) << 16;
  return v.f;
}

#define GLD16(gp, lp)                                                          \
  __builtin_amdgcn_global_load_lds(                                            \
      (const __attribute__((address_space(1))) void*)(gp),                     \
      (__attribute__((address_space(3))) void*)(lp), 16, 0, 0)

// counted-vmcnt wait (never emits compiler drain); raw barrier + sched fence
#define WAITVM(N) asm volatile("s_waitcnt vmcnt(" #N ")" ::: "memory")
#define BAR()                                                                  \
  do {                                                                         \
    __builtin_amdgcn_sched_barrier(0);                                         \
    __builtin_amdgcn_s_barrier();                                              \
    __builtin_amdgcn_sched_barrier(0);                                         \
  } while (0)

// prefix-from-counts helper: returns offset of expert e, sets cnt
__device__ __forceinline__ int expert_off(const int* __restrict__ counts, int e, int* cnt) {
  int off = 0, s = 0;
#pragma unroll
  for (int i = 0; i < NE; i++) { if (i == e) off = s; s += counts[i]; }
  *cnt = counts[e];
  return off;
}

// ---------------------------------------------------------------------------
// Fused transpose + fp32->bf16 for all three weight tensors in ONE launch.
// ---------------------------------------------------------------------------
__global__ __launch_bounds__(256) void k_transpose(
    const float* __restrict__ W, const float* __restrict__ V,
    const float* __restrict__ Wout, unsigned short* __restrict__ B1t,
    unsigned short* __restrict__ B2t, int* __restrict__ counts) {
  if (blockIdx.z == 0 && blockIdx.x == 0 && blockIdx.y == 0 && threadIdx.x < NE)
    counts[threadIdx.x] = 0;

  const int z = blockIdx.z;
  const float* s;
  unsigned short* d;
  int R, C, xt, yt;
  if (z < 16) {
    const int e = z & 7;
    s = ((z < 8) ? W : V) + (size_t)e * DM * DH;
    d = B1t + (size_t)e * 4096 * DM + (size_t)((z < 8) ? 0 : DH) * DM;
    R = DM; C = DH; xt = blockIdx.x; yt = blockIdx.y;      // 32 x 16 tiles
  } else {
    const int e = z - 16;
    s = Wout + (size_t)e * DH * DM;
    d = B2t + (size_t)e * DM * DH;
    R = DH; C = DM;
    const int flat = blockIdx.x * 16 + blockIdx.y;          // 0..511 = 16 x 32
    xt = flat & 15; yt = flat >> 4;
  }
  const int c0 = xt * 64, r0 = yt * 64;
  __shared__ float tile[64][65];
  const int t = threadIdx.x;
  {
    const int cc = (t & 15) * 4;
#pragma unroll
    for (int j = 0; j < 4; j++) {
      const int r = (t >> 4) + j * 16;
      const float4 v = *(const float4*)(s + (size_t)(r0 + r) * C + c0 + cc);
      tile[r][cc + 0] = v.x; tile[r][cc + 1] = v.y;
      tile[r][cc + 2] = v.z; tile[r][cc + 3] = v.w;
    }
  }
  __syncthreads();
  {
    const int r8 = (t & 7) * 8;
#pragma unroll
    for (int j = 0; j < 2; j++) {
      const int c = (t >> 3) + j * 32;
      u16x8 o;
#pragma unroll
      for (int i = 0; i < 8; i++) o[i] = f2bf(tile[r8 + i][c]);
      *(u16x8*)(d + (size_t)(c0 + c) * R + r0 + r8) = o;
    }
  }
}

// ---------------------------------------------------------------------------
// Router: fp32 logits, top-2, softmax, atomic per-expert slot assignment.
// ---------------------------------------------------------------------------
__global__ __launch_bounds__(256) void k_router(
    const float* __restrict__ x, const float* __restrict__ rw,
    const float* __restrict__ rb, int* __restrict__ counts,
    int* __restrict__ meta_e, int* __restrict__ meta_idx,
    float* __restrict__ meta_p) {
  const int wv = threadIdx.x >> 6;
  const int l  = threadIdx.x & 63;
  const int tk = blockIdx.x * 4 + wv;
  const float* xr = x + (size_t)tk * DM;

  float acc[NE];
#pragma unroll
  for (int e = 0; e < NE; e++) acc[e] = 0.f;
#pragma unroll 4
  for (int i = 0; i < DM / 64; i++) {
    const float xv = xr[i * 64 + l];
#pragma unroll
    for (int e = 0; e < NE; e++) acc[e] += xv * rw[e * DM + i * 64 + l];
  }
#pragma unroll
  for (int off = 32; off > 0; off >>= 1) {
#pragma unroll
    for (int e = 0; e < NE; e++) acc[e] += __shfl_xor(acc[e], off);
  }
#pragma unroll
  for (int e = 0; e < NE; e++) acc[e] += rb[e];

  float v0 = -1e30f; int e0 = 0;
#pragma unroll
  for (int e = 0; e < NE; e++) { if (acc[e] > v0) { v0 = acc[e]; e0 = e; } }
  float v1 = -1e30f; int e1 = 0;
#pragma unroll
  for (int e = 0; e < NE; e++) { if (e != e0 && acc[e] > v1) { v1 = acc[e]; e1 = e; } }
  const float p0 = 1.0f / (1.0f + __expf(v1 - v0));
  const float p1 = 1.0f - p0;

  if (l == 0) {
    const int i0 = atomicAdd(&counts[e0], 1);
    const int i1 = atomicAdd(&counts[e1], 1);
    meta_e[tk * 2 + 0] = e0;  meta_e[tk * 2 + 1] = e1;
    meta_idx[tk * 2 + 0] = i0; meta_idx[tk * 2 + 1] = i1;
    meta_p[tk * 2 + 0] = p0;  meta_p[tk * 2 + 1] = p1;
  }
}

// ---------------------------------------------------------------------------
// Gather: one block per TOKEN; read x row once, write both routed slots.
// ---------------------------------------------------------------------------
__global__ __launch_bounds__(256) void k_gather(
    const float* __restrict__ x, const int* __restrict__ meta_e,
    const int* __restrict__ meta_idx, const int* __restrict__ counts,
    unsigned short* __restrict__ Xg) {
  const int tk = blockIdx.x;
  int offs[NE];
  { int s = 0;
#pragma unroll
    for (int e = 0; e < NE; e++) { offs[e] = s; s += counts[e]; } }
  const int s0 = tk * 2, s1 = s0 + 1;
  const int g0 = offs[meta_e[s0]] + meta_idx[s0];
  const int g1 = offs[meta_e[s1]] + meta_idx[s1];
  const float4 v = ((const float4*)(x + (size_t)tk * DM))[threadIdx.x];
  ushort4 o;
  o.x = f2bf(v.x); o.y = f2bf(v.y); o.z = f2bf(v.z); o.w = f2bf(v.w);
  *(ushort4*)(Xg + (size_t)g0 * DM + threadIdx.x * 4) = o;
  *(ushort4*)(Xg + (size_t)g1 * DM + threadIdx.x * 4) = o;
}

// ---------------------------------------------------------------------------
// GEMM1 fused SwiGLU — 8-wave 256(m)x128(h) tile, K pipelined in 32-wide
// slabs through a 4-slot LDS ring (128 KB), prefetch depth 3, counted
// vmcnt (never 0 in main loop), raw s_barrier (no compiler drain), T2
// XOR-swizzle (row-preserving involution, applied to BOTH the staged
// global source k-offset and the ds_read address), T5 setprio around MFMA.
// Per-slab per-thread loads: A0,A1,W,V = 4 -> steady wait vmcnt(8)
// (slabs s+2,s+3 in flight; slab s+1 guaranteed complete in ALL waves
// because every wave executes WAITVM(8) before the shared barrier).
// ---------------------------------------------------------------------------
__global__ __launch_bounds__(512, 2) void k_gemm1(
    const unsigned short* __restrict__ Xg, const unsigned short* __restrict__ B1t,
    unsigned short* __restrict__ G, const int* __restrict__ counts) {
  const int e = blockIdx.z;
  int cnt;
  const int off = expert_off(counts, e, &cnt);
  const int mt = blockIdx.y;
  if (mt * 256 >= cnt) return;
  const int h0 = blockIdx.x * 128;
  const int row_base = off + mt * 256;

  __shared__ unsigned short As[4][256 * 32];   // 64 KB
  __shared__ unsigned short Ws[4][128 * 32];   // 32 KB
  __shared__ unsigned short Vs[4][128 * 32];   // 32 KB  -> 128 KB total

  const int t = threadIdx.x;
  const int l = t & 63;
  const int w = t >> 6;          // 0..7
  const int wm = (w >> 1) * 64;  // 4 m-waves
  const int wn = (w & 1) * 64;   // 2 n-waves
  const int lr = l & 15;
  const int kq = (l >> 4) * 8;

  const unsigned short* Bw = B1t + ((size_t)e * 4096 + h0) * DM;
  const unsigned short* Bv = Bw + (size_t)DH * DM;

  // staging geometry (slab-invariant). Chunk c covers LDS bytes [16c,16c+16):
  // row = c>>2, phys 16B slot = c&3; source k-offset = (slot ^ ((row>>1)&3))*8
  // so reading with idx ^ ((row>>1)&3)<<3 recovers logical data (involution).
  const int cA0 = t, cA1 = t + 512;
  const int rA0 = cA0 >> 2, rA1 = cA1 >> 2;
  const int kA0 = ((cA0 & 3) ^ ((rA0 >> 1) & 3)) << 3;
  const int kA1 = ((cA1 & 3) ^ ((rA1 >> 1) & 3)) << 3;
  const size_t aoff0 = (size_t)min(row_base + rA0, NSLOT - 1) * DM + kA0;
  const size_t aoff1 = (size_t)min(row_base + rA1, NSLOT - 1) * DM + kA1;
  const int rB = t >> 2;
  const int kB = ((t & 3) ^ ((rB >> 1) & 3)) << 3;
  const size_t boff = (size_t)rB * DM + kB;

#define STAGE1(s)                                                              \
  do {                                                                         \
    const int k0_ = (s) * 32;                                                  \
    unsigned short* As_ = As[(s) & 3];                                         \
    unsigned short* Ws_ = Ws[(s) & 3];                                         \
    unsigned short* Vs_ = Vs[(s) & 3];                                         \
    GLD16(Xg + aoff0 + k0_, &As_[cA0 * 8]);                                    \
    GLD16(Xg + aoff1 + k0_, &As_[cA1 * 8]);                                    \
    GLD16(Bw + boff + k0_, &Ws_[t * 8]);                                       \
    GLD16(Bv + boff + k0_, &Vs_[t * 8]);                                       \
  } while (0)

  f32x4 acc_a[4][4], acc_b[4][4];
  const f32x4 z4 = {0.f, 0.f, 0.f, 0.f};
#pragma unroll
  for (int i = 0; i < 4; i++)
#pragma unroll
    for (int j = 0; j < 4; j++) { acc_a[i][j] = z4; acc_b[i][j] = z4; }

  STAGE1(0); STAGE1(1); STAGE1(2);   // 12 loads in flight
  WAITVM(8);                         // slab 0 complete (1,2 still in flight)
  BAR();

  const int NS = DM / 32;  // 32 slabs
#pragma unroll 2
  for (int s = 0; s < NS; s++) {
    if (s + 3 < NS) STAGE1(s + 3);   // writes ring slot (s-1)&3: safe, all
                                     // waves done reading it (prev barrier)
    const unsigned short* Asl = As[s & 3];
    const unsigned short* Wsl = Ws[s & 3];
    const unsigned short* Vsl = Vs[s & 3];
    bf16x8_t af[4], wf[4], vf[4];
#pragma unroll
    for (int mi = 0; mi < 4; mi++) {
      const int row = wm + mi * 16 + lr;
      af[mi] = *(const bf16x8_t*)&Asl[(row * 32 + kq) ^ (((row >> 1) & 3) << 3)];
    }
#pragma unroll
    for (int ni = 0; ni < 4; ni++) {
      const int row = wn + ni * 16 + lr;
      const int idx = (row * 32 + kq) ^ (((row >> 1) & 3) << 3);
      wf[ni] = *(const bf16x8_t*)&Wsl[idx];
      vf[ni] = *(const bf16x8_t*)&Vsl[idx];
    }
    __builtin_amdgcn_s_setprio(1);
#pragma unroll
    for (int mi = 0; mi < 4; mi++)
#pragma unroll
      for (int ni = 0; ni < 4; ni++) {
        acc_a[mi][ni] = __builtin_amdgcn_mfma_f32_16x16x32_bf16(af[mi], wf[ni], acc_a[mi][ni], 0, 0, 0);
        acc_b[mi][ni] = __builtin_amdgcn_mfma_f32_16x16x32_bf16(af[mi], vf[ni], acc_b[mi][ni], 0, 0, 0);
      }
    __builtin_amdgcn_s_setprio(0);
    // ensure slab s+1 staged before next iteration's ds_reads
    if (s < NS - 3)       { WAITVM(8); }
    else if (s == NS - 3) { WAITVM(4); }
    else if (s == NS - 2) { WAITVM(0); }
    if (s < NS - 1) BAR();
  }
#undef STAGE1

  const int q4 = (l >> 4) * 4;
#pragma unroll
  for (int mi = 0; mi < 4; mi++) {
#pragma unroll
    for (int r = 0; r < 4; r++) {
      const int mloc = mt * 256 + wm + mi * 16 + q4 + r;
      if (mloc >= cnt) continue;
      unsigned short* grow = G + (size_t)(off + mloc) * DH;
#pragma unroll
      for (int ni = 0; ni < 4; ni++) {
        const int h = h0 + wn + ni * 16 + lr;
        const float a = acc_a[mi][ni][r];
        const float b = acc_b[mi][ni][r];
        const float sgl = b / (1.0f + __expf(-b));  // silu(b)
        grow[h] = f2bf(a * sgl);
      }
    }
  }
}

// ---------------------------------------------------------------------------
// GEMM2 — same pipelined structure, 256(m)x128(n) tile, split-K x2,
// 4-slot ring (96 KB), 3 loads/slab -> steady wait vmcnt(6).
// ---------------------------------------------------------------------------
__global__ __launch_bounds__(512, 2) void k_gemm2(
    const unsigned short* __restrict__ G, const unsigned short* __restrict__ B2t,
    unsigned short* __restrict__ Y, const int* __restrict__ counts) {
  const int z = blockIdx.z;
  const int e = z & 7;
  const int half = z >> 3;
  int cnt;
  const int off = expert_off(counts, e, &cnt);
  const int mt = blockIdx.y;
  if (mt * 256 >= cnt) return;
  const int n0 = blockIdx.x * 128;
  const int row_base = off + mt * 256;
  const int kbase = half * 1024;

  __shared__ unsigned short As[4][256 * 32];   // 64 KB
  __shared__ unsigned short Bs[4][128 * 32];   // 32 KB -> 96 KB total

  const int t = threadIdx.x;
  const int l = t & 63;
  const int w = t >> 6;
  const int wm = (w >> 1) * 64;
  const int wn = (w & 1) * 64;
  const int lr = l & 15;
  const int kq = (l >> 4) * 8;

  const unsigned short* Bp = B2t + ((size_t)e * DM + n0) * DH;

  const int cA0 = t, cA1 = t + 512;
  const int rA0 = cA0 >> 2, rA1 = cA1 >> 2;
  const int kA0 = ((cA0 & 3) ^ ((rA0 >> 1) & 3)) << 3;
  const int kA1 = ((cA1 & 3) ^ ((rA1 >> 1) & 3)) << 3;
  const size_t aoff0 = (size_t)min(row_base + rA0, NSLOT - 1) * DH + kA0;
  const size_t aoff1 = (size_t)min(row_base + rA1, NSLOT - 1) * DH + kA1;
  const int rB = t >> 2;
  const int kB = ((t & 3) ^ ((rB >> 1) & 3)) << 3;
  const size_t boff = (size_t)rB * DH + kB;

#define STAGE2(s)                                                              \
  do {                                                                         \
    const int k0_ = kbase + (s) * 32;                                          \
    unsigned short* As_ = As[(s) & 3];                                         \
    unsigned short* Bs_ = Bs[(s) & 3];                                         \
    GLD16(G + aoff0 + k0_, &As_[cA0 * 8]);                                     \
    GLD16(G + aoff1 + k0_, &As_[cA1 * 8]);                                     \
    GLD16(Bp + boff + k0_, &Bs_[t * 8]);                                       \
  } while (0)

  f32x4 acc[4][4];
  const f32x4 z4 = {0.f, 0.f, 0.f, 0.f};
#pragma unroll
  for (int i = 0; i < 4; i++)
#pragma unroll
    for (int j = 0; j < 4; j++) acc[i][j] = z4;

  STAGE2(0); STAGE2(1); STAGE2(2);   // 9 loads in flight
  WAITVM(6);                         // slab 0 complete
  BAR();

  const int NS = 1024 / 32;  // 32 slabs per K-half
#pragma unroll 2
  for (int s = 0; s < NS; s++) {
    if (s + 3 < NS) STAGE2(s + 3);
    const unsigned short* Asl = As[s & 3];
    const unsigned short* Bsl = Bs[s & 3];
    bf16x8_t af[4], bf[4];
#pragma unroll
    for (int mi = 0; mi < 4; mi++) {
      const int row = wm + mi * 16 + lr;
      af[mi] = *(const bf16x8_t*)&Asl[(row * 32 + kq) ^ (((row >> 1) & 3) << 3)];
    }
#pragma unroll
    for (int ni = 0; ni < 4; ni++) {
      const int row = wn + ni * 16 + lr;
      bf[ni] = *(const bf16x8_t*)&Bsl[(row * 32 + kq) ^ (((row >> 1) & 3) << 3)];
    }
    __builtin_amdgcn_s_setprio(1);
#pragma unroll
    for (int mi = 0; mi < 4; mi++)
#pragma unroll
      for (int ni = 0; ni < 4; ni++)
        acc[mi][ni] = __builtin_amdgcn_mfma_f32_16x16x32_bf16(af[mi], bf[ni], acc[mi][ni], 0, 0, 0);
    __builtin_amdgcn_s_setprio(0);
    if (s < NS - 3)       { WAITVM(6); }
    else if (s == NS - 3) { WAITVM(3); }
    else if (s == NS - 2) { WAITVM(0); }
    if (s < NS - 1) BAR();
  }
#undef STAGE2

  unsigned short* Yh = Y + (size_t)half * NSLOT * DM;
  const int q4 = (l >> 4) * 4;
#pragma unroll
  for (int mi = 0; mi < 4; mi++) {
#pragma unroll
    for (int r = 0; r < 4; r++) {
      const int mloc = mt * 256 + wm + mi * 16 + q4 + r;
      if (mloc >= cnt) continue;
      unsigned short* yrow = Yh + (size_t)(off + mloc) * DM;
#pragma unroll
      for (int ni = 0; ni < 4; ni++)
        yrow[n0 + wn + ni * 16 + lr] = f2bf(acc[mi][ni][r]);
    }
  }
}

// ---------------------------------------------------------------------------
// Combine: out[tok] = p0*(Y0[g0]+Y1[g0]) + p1*(Y0[g1]+Y1[g1]); Y is bf16.
// ---------------------------------------------------------------------------
__global__ __launch_bounds__(256) void k_combine(
    const unsigned short* __restrict__ Y, const int* __restrict__ meta_e,
    const int* __restrict__ meta_idx, const float* __restrict__ meta_p,
    const int* __restrict__ counts, float* __restrict__ out) {
  const int tk = blockIdx.x;
  int offs[NE];
  { int s = 0;
#pragma unroll
    for (int e = 0; e < NE; e++) { offs[e] = s; s += counts[e]; } }
  const int s0 = tk * 2, s1 = s0 + 1;
  const int g0 = offs[meta_e[s0]] + meta_idx[s0];
  const int g1 = offs[meta_e[s1]] + meta_idx[s1];
  const float w0 = meta_p[s0], w1 = meta_p[s1];
  const unsigned short* Y1 = Y + (size_t)NSLOT * DM;
  const ushort4 a0 = ((const ushort4*)(Y  + (size_t)g0 * DM))[threadIdx.x];
  const ushort4 a1 = ((const ushort4*)(Y1 + (size_t)g0 * DM))[threadIdx.x];
  const ushort4 b0 = ((const ushort4*)(Y  + (size_t)g1 * DM))[threadIdx.x];
  const ushort4 b1 = ((const ushort4*)(Y1 + (size_t)g1 * DM))[threadIdx.x];
  float4 o;
  o.x = w0 * (bf2f(a0.x) + bf2f(a1.x)) + w1 * (bf2f(b0.x) + bf2f(b1.x));
  o.y = w0 * (bf2f(a0.y) + bf2f(a1.y)) + w1 * (bf2f(b0.y) + bf2f(b1.y));
  o.z = w0 * (bf2f(a0.z) + bf2f(a1.z)) + w1 * (bf2f(b0.z) + bf2f(b1.z));
  o.w = w0 * (bf2f(a0.w) + bf2f(a1.w)) + w1 * (bf2f(b0.w) + bf2f(b1.w));
  ((float4*)(out + (size_t)tk * DM))[threadIdx.x] = o;
}

// ---------------------------------------------------------------------------
extern "C" void kernel_launch(void* const* d_in, const int* in_sizes, int n_in,
                              void* d_out, int out_size, void* d_ws, size_t ws_size,
                              hipStream_t stream) {
  const float* x    = (const float*)d_in[0];  // [2,2048,1024]
  const float* rw   = (const float*)d_in[1];  // [8,1024]
  const float* rb   = (const float*)d_in[2];  // [8]
  const float* W    = (const float*)d_in[3];  // [8,1024,2048]
  const float* V    = (const float*)d_in[4];  // [8,1024,2048]
  const float* Wout = (const float*)d_in[5];  // [8,2048,1024]
  float* out = (float*)d_out;

  // workspace carve-up (~145 MB); Y (bf16 [2][NSLOT][DM] = 32 MB) aliases
  // B1t (64 MB, dead after gemm1)
  char* p = (char*)d_ws;
  unsigned short* B1t = (unsigned short*)p; p += (size_t)NE * 4096 * DM * 2;   // 64 MB [e][n=4096][k=1024]
  unsigned short* Y   = (unsigned short*)B1t;                                  // alias: [2][NSLOT][DM] bf16
  unsigned short* B2t = (unsigned short*)p; p += (size_t)NE * DM * DH * 2;     // 32 MB [e][n=1024][k=2048]
  unsigned short* Xg  = (unsigned short*)p; p += (size_t)NSLOT * DM * 2;       // 16 MB
  unsigned short* G   = (unsigned short*)p; p += (size_t)NSLOT * DH * 2;       // 32 MB
  int*   counts      = (int*)p;   p += 256;
  int*   meta_e      = (int*)p;   p += (size_t)N_TOK * 2 * 4;
  int*   meta_idx    = (int*)p;   p += (size_t)N_TOK * 2 * 4;
  float* meta_p      = (float*)p; p += (size_t)N_TOK * 2 * 4;

  k_transpose<<<dim3(32, 16, 24), 256, 0, stream>>>(W, V, Wout, B1t, B2t, counts);
  k_router<<<N_TOK / 4, 256, 0, stream>>>(x, rw, rb, counts, meta_e, meta_idx, meta_p);
  k_gather<<<N_TOK, 256, 0, stream>>>(x, meta_e, meta_idx, counts, Xg);
  k_gemm1<<<dim3(DH / 128, NSLOT / 256, NE), 512, 0, stream>>>(Xg, B1t, G, counts);
  k_gemm2<<<dim3(DM / 128, NSLOT / 256, 2 * NE), 512, 0, stream>>>(G, B2t, Y, counts);
  k_combine<<<N_TOK, 256, 0, stream>>>(Y, meta_e, meta_idx, meta_p, counts, out);
}

// Round 3
// 501.565 us; speedup vs baseline: 1.0946x; 1.0946x over previous
//
#include <hip/hip_runtime.h>
#include <cstdint>
#include <cstddef>

// Problem constants
#define N_TOK 4096     // B*T tokens
#define DM    1024     // d_model
#define DH    2048     // d_hidden
#define NE    8        // experts
#define NSLOT 8192     // total routed slots = N_TOK * top_k

typedef short bf16x8_t __attribute__((ext_vector_type(8)));  // 8 bf16 (4 VGPRs)
typedef float f32x4    __attribute__((ext_vector_type(4)));
typedef unsigned short u16x8 __attribute__((ext_vector_type(8)));

__device__ __forceinline__ unsigned short f2bf(float f) {
  union { float f; unsigned int u; } v; v.f = f;
  unsigned int u = v.u;
  u += 0x7fffu + ((u >> 16) & 1u);   // RNE
  return (unsigned short)(u >> 16);
}

__device__ __forceinline__ float bf2f(unsigned short h) {
  union { unsigned int u; float f; } v; v.u = ((unsigned int)h) << 16;
  return v.f;
}

#define GLD16(gp, lp)                                                          \
  __builtin_amdgcn_global_load_lds(                                            \
      (const __attribute__((address_space(1))) void*)(gp),                     \
      (__attribute__((address_space(3))) void*)(lp), 16, 0, 0)

// prefix-from-counts helper: returns offset of expert e, sets cnt
__device__ __forceinline__ int expert_off(const int* __restrict__ counts, int e, int* cnt) {
  int off = 0, s = 0;
#pragma unroll
  for (int i = 0; i < NE; i++) { if (i == e) off = s; s += counts[i]; }
  *cnt = counts[e];
  return off;
}

// ---------------------------------------------------------------------------
// Fused transpose + fp32->bf16 for all three weight tensors in ONE launch.
// ---------------------------------------------------------------------------
__global__ __launch_bounds__(256) void k_transpose(
    const float* __restrict__ W, const float* __restrict__ V,
    const float* __restrict__ Wout, unsigned short* __restrict__ B1t,
    unsigned short* __restrict__ B2t, int* __restrict__ counts) {
  if (blockIdx.z == 0 && blockIdx.x == 0 && blockIdx.y == 0 && threadIdx.x < NE)
    counts[threadIdx.x] = 0;

  const int z = blockIdx.z;
  const float* s;
  unsigned short* d;
  int R, C, xt, yt;
  if (z < 16) {
    const int e = z & 7;
    s = ((z < 8) ? W : V) + (size_t)e * DM * DH;
    d = B1t + (size_t)e * 4096 * DM + (size_t)((z < 8) ? 0 : DH) * DM;
    R = DM; C = DH; xt = blockIdx.x; yt = blockIdx.y;      // 32 x 16 tiles
  } else {
    const int e = z - 16;
    s = Wout + (size_t)e * DH * DM;
    d = B2t + (size_t)e * DM * DH;
    R = DH; C = DM;
    const int flat = blockIdx.x * 16 + blockIdx.y;          // 0..511 = 16 x 32
    xt = flat & 15; yt = flat >> 4;
  }
  const int c0 = xt * 64, r0 = yt * 64;
  __shared__ float tile[64][65];
  const int t = threadIdx.x;
  {
    const int cc = (t & 15) * 4;
#pragma unroll
    for (int j = 0; j < 4; j++) {
      const int r = (t >> 4) + j * 16;
      const float4 v = *(const float4*)(s + (size_t)(r0 + r) * C + c0 + cc);
      tile[r][cc + 0] = v.x; tile[r][cc + 1] = v.y;
      tile[r][cc + 2] = v.z; tile[r][cc + 3] = v.w;
    }
  }
  __syncthreads();
  {
    const int r8 = (t & 7) * 8;
#pragma unroll
    for (int j = 0; j < 2; j++) {
      const int c = (t >> 3) + j * 32;
      u16x8 o;
#pragma unroll
      for (int i = 0; i < 8; i++) o[i] = f2bf(tile[r8 + i][c]);
      *(u16x8*)(d + (size_t)(c0 + c) * R + r0 + r8) = o;
    }
  }
}

// ---------------------------------------------------------------------------
// Router: fp32 logits, top-2, softmax, atomic per-expert slot assignment.
// ---------------------------------------------------------------------------
__global__ __launch_bounds__(256) void k_router(
    const float* __restrict__ x, const float* __restrict__ rw,
    const float* __restrict__ rb, int* __restrict__ counts,
    int* __restrict__ meta_e, int* __restrict__ meta_idx,
    float* __restrict__ meta_p) {
  const int wv = threadIdx.x >> 6;
  const int l  = threadIdx.x & 63;
  const int tk = blockIdx.x * 4 + wv;
  const float* xr = x + (size_t)tk * DM;

  float acc[NE];
#pragma unroll
  for (int e = 0; e < NE; e++) acc[e] = 0.f;
#pragma unroll 4
  for (int i = 0; i < DM / 64; i++) {
    const float xv = xr[i * 64 + l];
#pragma unroll
    for (int e = 0; e < NE; e++) acc[e] += xv * rw[e * DM + i * 64 + l];
  }
#pragma unroll
  for (int off = 32; off > 0; off >>= 1) {
#pragma unroll
    for (int e = 0; e < NE; e++) acc[e] += __shfl_xor(acc[e], off);
  }
#pragma unroll
  for (int e = 0; e < NE; e++) acc[e] += rb[e];

  float v0 = -1e30f; int e0 = 0;
#pragma unroll
  for (int e = 0; e < NE; e++) { if (acc[e] > v0) { v0 = acc[e]; e0 = e; } }
  float v1 = -1e30f; int e1 = 0;
#pragma unroll
  for (int e = 0; e < NE; e++) { if (e != e0 && acc[e] > v1) { v1 = acc[e]; e1 = e; } }
  const float p0 = 1.0f / (1.0f + __expf(v1 - v0));
  const float p1 = 1.0f - p0;

  if (l == 0) {
    const int i0 = atomicAdd(&counts[e0], 1);
    const int i1 = atomicAdd(&counts[e1], 1);
    meta_e[tk * 2 + 0] = e0;  meta_e[tk * 2 + 1] = e1;
    meta_idx[tk * 2 + 0] = i0; meta_idx[tk * 2 + 1] = i1;
    meta_p[tk * 2 + 0] = p0;  meta_p[tk * 2 + 1] = p1;
  }
}

// ---------------------------------------------------------------------------
// Gather: one block per TOKEN; read x row once, write both routed slots.
// ---------------------------------------------------------------------------
__global__ __launch_bounds__(256) void k_gather(
    const float* __restrict__ x, const int* __restrict__ meta_e,
    const int* __restrict__ meta_idx, const int* __restrict__ counts,
    unsigned short* __restrict__ Xg) {
  const int tk = blockIdx.x;
  int offs[NE];
  { int s = 0;
#pragma unroll
    for (int e = 0; e < NE; e++) { offs[e] = s; s += counts[e]; } }
  const int s0 = tk * 2, s1 = s0 + 1;
  const int g0 = offs[meta_e[s0]] + meta_idx[s0];
  const int g1 = offs[meta_e[s1]] + meta_idx[s1];
  const float4 v = ((const float4*)(x + (size_t)tk * DM))[threadIdx.x];
  ushort4 o;
  o.x = f2bf(v.x); o.y = f2bf(v.y); o.z = f2bf(v.z); o.w = f2bf(v.w);
  *(ushort4*)(Xg + (size_t)g0 * DM + threadIdx.x * 4) = o;
  *(ushort4*)(Xg + (size_t)g1 * DM + threadIdx.x * 4) = o;
}

// ---------------------------------------------------------------------------
// GEMM1 fused SwiGLU — round-0 geometry (128m x 128h tile, 4 waves, 2-3
// blocks/CU) + minimum-2-phase double buffer (T3 recipe): BK=32 slabs,
// 2 LDS buffers (48 KB), per iter {ds_read frags(cur); STAGE(next->cur^1);
// MFMA; __syncthreads}. Stage latency hides under ~1200 cyc of compute
// before the barrier's vmcnt drain. T2 XOR-swizzle (validated round 2:
// conflicts 6.59M -> 0, bit-exact) on both stage source and ds_read addr.
// ---------------------------------------------------------------------------
__global__ __launch_bounds__(256, 2) void k_gemm1(
    const unsigned short* __restrict__ Xg, const unsigned short* __restrict__ B1t,
    unsigned short* __restrict__ G, const int* __restrict__ counts) {
  const int e = blockIdx.z;
  int cnt;
  const int off = expert_off(counts, e, &cnt);
  const int mt = blockIdx.y;
  if (mt * 128 >= cnt) return;
  const int h0 = blockIdx.x * 128;
  const int row_base = off + mt * 128;

  __shared__ unsigned short As[2][128 * 32];   // 16 KB
  __shared__ unsigned short Ws[2][128 * 32];   // 16 KB
  __shared__ unsigned short Vs[2][128 * 32];   // 16 KB -> 48 KB total

  const int t = threadIdx.x;
  const int l = t & 63;
  const int w = t >> 6;          // 0..3
  const int wm = (w >> 1) * 64;
  const int wn = (w & 1) * 64;
  const int lr = l & 15;
  const int kq = (l >> 4) * 8;

  const unsigned short* Bw = B1t + ((size_t)e * 4096 + h0) * DM;
  const unsigned short* Bv = Bw + (size_t)DH * DM;

  // staging geometry: 512 16B-chunks per 128x32 buf; 2 chunks/thread.
  // chunk c: row=c>>2, phys slot=c&3; swizzled source k = (slot^((row>>1)&3))*8
  const int c0 = t, c1 = t + 256;
  const int r0 = c0 >> 2, r1 = c1 >> 2;
  const int k0s = ((c0 & 3) ^ ((r0 >> 1) & 3)) << 3;
  const int k1s = ((c1 & 3) ^ ((r1 >> 1) & 3)) << 3;
  const size_t aoff0 = (size_t)min(row_base + r0, NSLOT - 1) * DM + k0s;
  const size_t aoff1 = (size_t)min(row_base + r1, NSLOT - 1) * DM + k1s;
  const size_t boff0 = (size_t)r0 * DM + k0s;
  const size_t boff1 = (size_t)r1 * DM + k1s;

#define STG1(buf, kk)                                                          \
  do {                                                                         \
    GLD16(Xg + aoff0 + (kk), &As[buf][c0 * 8]);                                \
    GLD16(Xg + aoff1 + (kk), &As[buf][c1 * 8]);                                \
    GLD16(Bw + boff0 + (kk), &Ws[buf][c0 * 8]);                                \
    GLD16(Bw + boff1 + (kk), &Ws[buf][c1 * 8]);                                \
    GLD16(Bv + boff0 + (kk), &Vs[buf][c0 * 8]);                                \
    GLD16(Bv + boff1 + (kk), &Vs[buf][c1 * 8]);                                \
  } while (0)

  f32x4 acc_a[4][4], acc_b[4][4];
  const f32x4 z4 = {0.f, 0.f, 0.f, 0.f};
#pragma unroll
  for (int i = 0; i < 4; i++)
#pragma unroll
    for (int j = 0; j < 4; j++) { acc_a[i][j] = z4; acc_b[i][j] = z4; }

  STG1(0, 0);
  __syncthreads();            // slab 0 landed

  const int NS = DM / 32;     // 32 slabs
  for (int s = 0; s < NS; s++) {
    const int cur = s & 1;
    // 1) register fragments from current buffer (before stage: keeps the
    //    compiler's LDS-alias conservatism from draining vmcnt here)
    bf16x8_t af[4], wf[4], vf[4];
#pragma unroll
    for (int mi = 0; mi < 4; mi++) {
      const int row = wm + mi * 16 + lr;
      af[mi] = *(const bf16x8_t*)&As[cur][(row * 32 + kq) ^ (((row >> 1) & 3) << 3)];
    }
#pragma unroll
    for (int ni = 0; ni < 4; ni++) {
      const int row = wn + ni * 16 + lr;
      const int idx = (row * 32 + kq) ^ (((row >> 1) & 3) << 3);
      wf[ni] = *(const bf16x8_t*)&Ws[cur][idx];
      vf[ni] = *(const bf16x8_t*)&Vs[cur][idx];
    }
    // 2) issue next slab's stage into the other buffer
    if (s + 1 < NS) STG1(cur ^ 1, (s + 1) * 32);
    // 3) compute (covers the stage's HBM/L2 latency)
#pragma unroll
    for (int mi = 0; mi < 4; mi++)
#pragma unroll
      for (int ni = 0; ni < 4; ni++) {
        acc_a[mi][ni] = __builtin_amdgcn_mfma_f32_16x16x32_bf16(af[mi], wf[ni], acc_a[mi][ni], 0, 0, 0);
        acc_b[mi][ni] = __builtin_amdgcn_mfma_f32_16x16x32_bf16(af[mi], vf[ni], acc_b[mi][ni], 0, 0, 0);
      }
    // 4) one barrier per slab: drains the stage, protects cur for overwrite
    __syncthreads();
  }
#undef STG1

  const int q4 = (l >> 4) * 4;
#pragma unroll
  for (int mi = 0; mi < 4; mi++) {
#pragma unroll
    for (int r = 0; r < 4; r++) {
      const int mloc = mt * 128 + wm + mi * 16 + q4 + r;
      if (mloc >= cnt) continue;
      unsigned short* grow = G + (size_t)(off + mloc) * DH;
#pragma unroll
      for (int ni = 0; ni < 4; ni++) {
        const int h = h0 + wn + ni * 16 + lr;
        const float a = acc_a[mi][ni][r];
        const float b = acc_b[mi][ni][r];
        const float sgl = b / (1.0f + __expf(-b));  // silu(b)
        grow[h] = f2bf(a * sgl);
      }
    }
  }
}

// ---------------------------------------------------------------------------
// GEMM2 — same minimum-2-phase dbuf structure, 128x128 tile, split-K x2,
// BK=32, 2 bufs (32 KB LDS), swizzled.
// ---------------------------------------------------------------------------
__global__ __launch_bounds__(256, 2) void k_gemm2(
    const unsigned short* __restrict__ G, const unsigned short* __restrict__ B2t,
    unsigned short* __restrict__ Y, const int* __restrict__ counts) {
  const int z = blockIdx.z;
  const int e = z & 7;
  const int half = z >> 3;
  int cnt;
  const int off = expert_off(counts, e, &cnt);
  const int mt = blockIdx.y;
  if (mt * 128 >= cnt) return;
  const int n0 = blockIdx.x * 128;
  const int row_base = off + mt * 128;
  const int kbase = half * 1024;

  __shared__ unsigned short As[2][128 * 32];
  __shared__ unsigned short Bs[2][128 * 32];   // 32 KB total

  const int t = threadIdx.x;
  const int l = t & 63;
  const int w = t >> 6;
  const int wm = (w >> 1) * 64;
  const int wn = (w & 1) * 64;
  const int lr = l & 15;
  const int kq = (l >> 4) * 8;

  const unsigned short* Bp = B2t + ((size_t)e * DM + n0) * DH;

  const int c0 = t, c1 = t + 256;
  const int r0 = c0 >> 2, r1 = c1 >> 2;
  const int k0s = ((c0 & 3) ^ ((r0 >> 1) & 3)) << 3;
  const int k1s = ((c1 & 3) ^ ((r1 >> 1) & 3)) << 3;
  const size_t aoff0 = (size_t)min(row_base + r0, NSLOT - 1) * DH + k0s;
  const size_t aoff1 = (size_t)min(row_base + r1, NSLOT - 1) * DH + k1s;
  const size_t boff0 = (size_t)r0 * DH + k0s;
  const size_t boff1 = (size_t)r1 * DH + k1s;

#define STG2(buf, kk)                                                          \
  do {                                                                         \
    GLD16(G + aoff0 + (kk), &As[buf][c0 * 8]);                                 \
    GLD16(G + aoff1 + (kk), &As[buf][c1 * 8]);                                 \
    GLD16(Bp + boff0 + (kk), &Bs[buf][c0 * 8]);                                \
    GLD16(Bp + boff1 + (kk), &Bs[buf][c1 * 8]);                                \
  } while (0)

  f32x4 acc[4][4];
  const f32x4 z4 = {0.f, 0.f, 0.f, 0.f};
#pragma unroll
  for (int i = 0; i < 4; i++)
#pragma unroll
    for (int j = 0; j < 4; j++) acc[i][j] = z4;

  STG2(0, kbase);
  __syncthreads();

  const int NS = 1024 / 32;   // 32 slabs per K-half
  for (int s = 0; s < NS; s++) {
    const int cur = s & 1;
    bf16x8_t af[4], bf[4];
#pragma unroll
    for (int mi = 0; mi < 4; mi++) {
      const int row = wm + mi * 16 + lr;
      af[mi] = *(const bf16x8_t*)&As[cur][(row * 32 + kq) ^ (((row >> 1) & 3) << 3)];
    }
#pragma unroll
    for (int ni = 0; ni < 4; ni++) {
      const int row = wn + ni * 16 + lr;
      bf[ni] = *(const bf16x8_t*)&Bs[cur][(row * 32 + kq) ^ (((row >> 1) & 3) << 3)];
    }
    if (s + 1 < NS) STG2(cur ^ 1, kbase + (s + 1) * 32);
#pragma unroll
    for (int mi = 0; mi < 4; mi++)
#pragma unroll
      for (int ni = 0; ni < 4; ni++)
        acc[mi][ni] = __builtin_amdgcn_mfma_f32_16x16x32_bf16(af[mi], bf[ni], acc[mi][ni], 0, 0, 0);
    __syncthreads();
  }
#undef STG2

  unsigned short* Yh = Y + (size_t)half * NSLOT * DM;
  const int q4 = (l >> 4) * 4;
#pragma unroll
  for (int mi = 0; mi < 4; mi++) {
#pragma unroll
    for (int r = 0; r < 4; r++) {
      const int mloc = mt * 128 + wm + mi * 16 + q4 + r;
      if (mloc >= cnt) continue;
      unsigned short* yrow = Yh + (size_t)(off + mloc) * DM;
#pragma unroll
      for (int ni = 0; ni < 4; ni++)
        yrow[n0 + wn + ni * 16 + lr] = f2bf(acc[mi][ni][r]);
    }
  }
}

// ---------------------------------------------------------------------------
// Combine: out[tok] = p0*(Y0[g0]+Y1[g0]) + p1*(Y0[g1]+Y1[g1]); Y is bf16.
// ---------------------------------------------------------------------------
__global__ __launch_bounds__(256) void k_combine(
    const unsigned short* __restrict__ Y, const int* __restrict__ meta_e,
    const int* __restrict__ meta_idx, const float* __restrict__ meta_p,
    const int* __restrict__ counts, float* __restrict__ out) {
  const int tk = blockIdx.x;
  int offs[NE];
  { int s = 0;
#pragma unroll
    for (int e = 0; e < NE; e++) { offs[e] = s; s += counts[e]; } }
  const int s0 = tk * 2, s1 = s0 + 1;
  const int g0 = offs[meta_e[s0]] + meta_idx[s0];
  const int g1 = offs[meta_e[s1]] + meta_idx[s1];
  const float w0 = meta_p[s0], w1 = meta_p[s1];
  const unsigned short* Y1 = Y + (size_t)NSLOT * DM;
  const ushort4 a0 = ((const ushort4*)(Y  + (size_t)g0 * DM))[threadIdx.x];
  const ushort4 a1 = ((const ushort4*)(Y1 + (size_t)g0 * DM))[threadIdx.x];
  const ushort4 b0 = ((const ushort4*)(Y  + (size_t)g1 * DM))[threadIdx.x];
  const ushort4 b1 = ((const ushort4*)(Y1 + (size_t)g1 * DM))[threadIdx.x];
  float4 o;
  o.x = w0 * (bf2f(a0.x) + bf2f(a1.x)) + w1 * (bf2f(b0.x) + bf2f(b1.x));
  o.y = w0 * (bf2f(a0.y) + bf2f(a1.y)) + w1 * (bf2f(b0.y) + bf2f(b1.y));
  o.z = w0 * (bf2f(a0.z) + bf2f(a1.z)) + w1 * (bf2f(b0.z) + bf2f(b1.z));
  o.w = w0 * (bf2f(a0.w) + bf2f(a1.w)) + w1 * (bf2f(b0.w) + bf2f(b1.w));
  ((float4*)(out + (size_t)tk * DM))[threadIdx.x] = o;
}

// ---------------------------------------------------------------------------
extern "C" void kernel_launch(void* const* d_in, const int* in_sizes, int n_in,
                              void* d_out, int out_size, void* d_ws, size_t ws_size,
                              hipStream_t stream) {
  const float* x    = (const float*)d_in[0];  // [2,2048,1024]
  const float* rw   = (const float*)d_in[1];  // [8,1024]
  const float* rb   = (const float*)d_in[2];  // [8]
  const float* W    = (const float*)d_in[3];  // [8,1024,2048]
  const float* V    = (const float*)d_in[4];  // [8,1024,2048]
  const float* Wout = (const float*)d_in[5];  // [8,2048,1024]
  float* out = (float*)d_out;

  // workspace carve-up (~145 MB); Y (bf16 [2][NSLOT][DM] = 32 MB) aliases
  // B1t (64 MB, dead after gemm1)
  char* p = (char*)d_ws;
  unsigned short* B1t = (unsigned short*)p; p += (size_t)NE * 4096 * DM * 2;   // 64 MB [e][n=4096][k=1024]
  unsigned short* Y   = (unsigned short*)B1t;                                  // alias: [2][NSLOT][DM] bf16
  unsigned short* B2t = (unsigned short*)p; p += (size_t)NE * DM * DH * 2;     // 32 MB [e][n=1024][k=2048]
  unsigned short* Xg  = (unsigned short*)p; p += (size_t)NSLOT * DM * 2;       // 16 MB
  unsigned short* G   = (unsigned short*)p; p += (size_t)NSLOT * DH * 2;       // 32 MB
  int*   counts      = (int*)p;   p += 256;
  int*   meta_e      = (int*)p;   p += (size_t)N_TOK * 2 * 4;
  int*   meta_idx    = (int*)p;   p += (size_t)N_TOK * 2 * 4;
  float* meta_p      = (float*)p; p += (size_t)N_TOK * 2 * 4;

  k_transpose<<<dim3(32, 16, 24), 256, 0, stream>>>(W, V, Wout, B1t, B2t, counts);
  k_router<<<N_TOK / 4, 256, 0, stream>>>(x, rw, rb, counts, meta_e, meta_idx, meta_p);
  k_gather<<<N_TOK, 256, 0, stream>>>(x, meta_e, meta_idx, counts, Xg);
  k_gemm1<<<dim3(DH / 128, NSLOT / 128, NE), 256, 0, stream>>>(Xg, B1t, G, counts);
  k_gemm2<<<dim3(DM / 128, NSLOT / 128, 2 * NE), 256, 0, stream>>>(G, B2t, Y, counts);
  k_combine<<<N_TOK, 256, 0, stream>>>(Y, meta_e, meta_idx, meta_p, counts, out);
}

// Round 4
// 442.510 us; speedup vs baseline: 1.2407x; 1.1335x over previous
//
#include <hip/hip_runtime.h>
#include <cstdint>
#include <cstddef>

// Problem constants
#define N_TOK 4096     // B*T tokens
#define DM    1024     // d_model
#define DH    2048     // d_hidden
#define NE    8        // experts
#define NSLOT 8192     // total routed slots = N_TOK * top_k

typedef short bf16x8_t __attribute__((ext_vector_type(8)));  // 8 bf16 (4 VGPRs)
typedef float f32x4    __attribute__((ext_vector_type(4)));
typedef unsigned short u16x8 __attribute__((ext_vector_type(8)));

__device__ __forceinline__ unsigned short f2bf(float f) {
  union { float f; unsigned int u; } v; v.f = f;
  unsigned int u = v.u;
  u += 0x7fffu + ((u >> 16) & 1u);   // RNE
  return (unsigned short)(u >> 16);
}

__device__ __forceinline__ float bf2f(unsigned short h) {
  union { unsigned int u; float f; } v; v.u = ((unsigned int)h) << 16;
  return v.f;
}

#define GLD16(gp, lp)                                                          \
  __builtin_amdgcn_global_load_lds(                                            \
      (const __attribute__((address_space(1))) void*)(gp),                     \
      (__attribute__((address_space(3))) void*)(lp), 16, 0, 0)

// prefix-from-counts helper: returns offset of expert e, sets cnt
__device__ __forceinline__ int expert_off(const int* __restrict__ counts, int e, int* cnt) {
  int off = 0, s = 0;
#pragma unroll
  for (int i = 0; i < NE; i++) { if (i == e) off = s; s += counts[i]; }
  *cnt = counts[e];
  return off;
}

// ---------------------------------------------------------------------------
// Fused transpose + fp32->bf16 for all three weight tensors in ONE launch.
// 128(row) x 64(col) tiles: writes become 256-B contiguous runs per column
// (16 lanes x 16 B), vs 128-B in the old 64x64 tiling. Reads stay 256-B runs.
// grid = (32, 8, 24): z<8 -> W, z<16 -> V ([DM][DH], 32 col-tiles x 8
// row-tiles), z>=16 -> Wout ([DH][DM], 16 x 16 via flat index).
// ---------------------------------------------------------------------------
__global__ __launch_bounds__(256) void k_transpose(
    const float* __restrict__ W, const float* __restrict__ V,
    const float* __restrict__ Wout, unsigned short* __restrict__ B1t,
    unsigned short* __restrict__ B2t, int* __restrict__ counts) {
  if (blockIdx.z == 0 && blockIdx.x == 0 && blockIdx.y == 0 && threadIdx.x < NE)
    counts[threadIdx.x] = 0;

  const int z = blockIdx.z;
  const float* s;
  unsigned short* d;
  int R, C, xt, yt;
  if (z < 16) {
    const int e = z & 7;
    s = ((z < 8) ? W : V) + (size_t)e * DM * DH;
    d = B1t + (size_t)e * 4096 * DM + (size_t)((z < 8) ? 0 : DH) * DM;
    R = DM; C = DH; xt = blockIdx.x; yt = blockIdx.y;       // 32 x 8 tiles
  } else {
    const int e = z - 16;
    s = Wout + (size_t)e * DH * DM;
    d = B2t + (size_t)e * DM * DH;
    R = DH; C = DM;
    const int flat = blockIdx.x * 8 + blockIdx.y;           // 0..255 = 16 x 16
    xt = flat & 15; yt = flat >> 4;
  }
  const int c0 = xt * 64, r0 = yt * 128;
  __shared__ float tile[128][65];
  const int t = threadIdx.x;
  {
    const int cc = (t & 15) * 4;
#pragma unroll
    for (int j = 0; j < 8; j++) {
      const int r = (t >> 4) + j * 16;
      const float4 v = *(const float4*)(s + (size_t)(r0 + r) * C + c0 + cc);
      tile[r][cc + 0] = v.x; tile[r][cc + 1] = v.y;
      tile[r][cc + 2] = v.z; tile[r][cc + 3] = v.w;
    }
  }
  __syncthreads();
  {
    const int r8 = (t & 15) * 8;          // 0..120
    const int cb = t >> 4;                // 0..15
#pragma unroll
    for (int pass = 0; pass < 4; pass++) {
      const int c = cb + pass * 16;       // 0..63
      u16x8 o;
#pragma unroll
      for (int i = 0; i < 8; i++) o[i] = f2bf(tile[r8 + i][c]);
      *(u16x8*)(d + (size_t)(c0 + c) * R + r0 + r8) = o;
    }
  }
}

// ---------------------------------------------------------------------------
// Router: fp32 logits, top-2, softmax. Two-level slot assignment: LDS
// atomics for per-block local indices, then ONE global atomicAdd per
// (block, expert) for the base (1024 global atomics total vs 8192 —
// same-address L2 RMW serialization was the suspected hidden cost).
// 32 tokens/block (4 waves x 8 tokens serially), grid = 128.
// ---------------------------------------------------------------------------
#define RTR_TOK 32
__global__ __launch_bounds__(256) void k_router(
    const float* __restrict__ x, const float* __restrict__ rw,
    const float* __restrict__ rb, int* __restrict__ counts,
    int* __restrict__ meta_e, int* __restrict__ meta_idx,
    float* __restrict__ meta_p) {
  __shared__ int lcnt[NE];
  __shared__ int lbase[NE];
  __shared__ int   tokE[RTR_TOK][2];
  __shared__ int   tokLi[RTR_TOK][2];
  __shared__ float tokP[RTR_TOK][2];

  const int wv = threadIdx.x >> 6;
  const int l  = threadIdx.x & 63;
  if (threadIdx.x < NE) lcnt[threadIdx.x] = 0;
  __syncthreads();

  for (int it = 0; it < RTR_TOK / 4; it++) {
    const int lt = wv * (RTR_TOK / 4) + it;
    const int tk = blockIdx.x * RTR_TOK + lt;
    const float* xr = x + (size_t)tk * DM;

    float acc[NE];
#pragma unroll
    for (int e = 0; e < NE; e++) acc[e] = 0.f;
#pragma unroll 4
    for (int i = 0; i < DM / 64; i++) {
      const float xv = xr[i * 64 + l];
#pragma unroll
      for (int e = 0; e < NE; e++) acc[e] += xv * rw[e * DM + i * 64 + l];
    }
#pragma unroll
    for (int off = 32; off > 0; off >>= 1) {
#pragma unroll
      for (int e = 0; e < NE; e++) acc[e] += __shfl_xor(acc[e], off);
    }
#pragma unroll
    for (int e = 0; e < NE; e++) acc[e] += rb[e];

    // top-2, strict > ascending scan (ties -> lower index, matches top_k)
    float v0 = -1e30f; int e0 = 0;
#pragma unroll
    for (int e = 0; e < NE; e++) { if (acc[e] > v0) { v0 = acc[e]; e0 = e; } }
    float v1 = -1e30f; int e1 = 0;
#pragma unroll
    for (int e = 0; e < NE; e++) { if (e != e0 && acc[e] > v1) { v1 = acc[e]; e1 = e; } }
    const float p0 = 1.0f / (1.0f + __expf(v1 - v0));
    const float p1 = 1.0f - p0;

    if (l == 0) {
      const int li0 = atomicAdd(&lcnt[e0], 1);
      const int li1 = atomicAdd(&lcnt[e1], 1);
      tokE[lt][0] = e0;  tokE[lt][1] = e1;
      tokLi[lt][0] = li0; tokLi[lt][1] = li1;
      tokP[lt][0] = p0;  tokP[lt][1] = p1;
    }
  }
  __syncthreads();
  if (threadIdx.x < NE)
    lbase[threadIdx.x] = atomicAdd(&counts[threadIdx.x], lcnt[threadIdx.x]);
  __syncthreads();
  if (threadIdx.x < RTR_TOK * 2) {
    const int lt = threadIdx.x >> 1, k = threadIdx.x & 1;
    const int tk = blockIdx.x * RTR_TOK + lt;
    const int e = tokE[lt][k];
    meta_e[tk * 2 + k] = e;
    meta_idx[tk * 2 + k] = lbase[e] + tokLi[lt][k];
    meta_p[tk * 2 + k] = tokP[lt][k];
  }
}

// ---------------------------------------------------------------------------
// Gather: one block per TOKEN; read x row once, write both routed slots.
// ---------------------------------------------------------------------------
__global__ __launch_bounds__(256) void k_gather(
    const float* __restrict__ x, const int* __restrict__ meta_e,
    const int* __restrict__ meta_idx, const int* __restrict__ counts,
    unsigned short* __restrict__ Xg) {
  const int tk = blockIdx.x;
  int offs[NE];
  { int s = 0;
#pragma unroll
    for (int e = 0; e < NE; e++) { offs[e] = s; s += counts[e]; } }
  const int s0 = tk * 2, s1 = s0 + 1;
  const int g0 = offs[meta_e[s0]] + meta_idx[s0];
  const int g1 = offs[meta_e[s1]] + meta_idx[s1];
  const float4 v = ((const float4*)(x + (size_t)tk * DM))[threadIdx.x];
  ushort4 o;
  o.x = f2bf(v.x); o.y = f2bf(v.y); o.z = f2bf(v.z); o.w = f2bf(v.w);
  *(ushort4*)(Xg + (size_t)g0 * DM + threadIdx.x * 4) = o;
  *(ushort4*)(Xg + (size_t)g1 * DM + threadIdx.x * 4) = o;
}

// ---------------------------------------------------------------------------
// GEMM1 fused SwiGLU — round-0 geometry (128m x 128h tile, 4 waves, 3
// blocks/CU LDS-limited) + 2-phase double buffer, BK=32, T2 XOR-swizzle
// (validated: conflicts 6.59M -> 0, bit-exact). 112 us measured; kept
// stable this round.
// ---------------------------------------------------------------------------
__global__ __launch_bounds__(256, 2) void k_gemm1(
    const unsigned short* __restrict__ Xg, const unsigned short* __restrict__ B1t,
    unsigned short* __restrict__ G, const int* __restrict__ counts) {
  const int e = blockIdx.z;
  int cnt;
  const int off = expert_off(counts, e, &cnt);
  const int mt = blockIdx.y;
  if (mt * 128 >= cnt) return;
  const int h0 = blockIdx.x * 128;
  const int row_base = off + mt * 128;

  __shared__ unsigned short As[2][128 * 32];   // 16 KB
  __shared__ unsigned short Ws[2][128 * 32];   // 16 KB
  __shared__ unsigned short Vs[2][128 * 32];   // 16 KB -> 48 KB total

  const int t = threadIdx.x;
  const int l = t & 63;
  const int w = t >> 6;          // 0..3
  const int wm = (w >> 1) * 64;
  const int wn = (w & 1) * 64;
  const int lr = l & 15;
  const int kq = (l >> 4) * 8;

  const unsigned short* Bw = B1t + ((size_t)e * 4096 + h0) * DM;
  const unsigned short* Bv = Bw + (size_t)DH * DM;

  // staging geometry: 512 16B-chunks per 128x32 buf; 2 chunks/thread.
  // chunk c: row=c>>2, phys slot=c&3; swizzled source k = (slot^((row>>1)&3))*8
  const int c0 = t, c1 = t + 256;
  const int r0 = c0 >> 2, r1 = c1 >> 2;
  const int k0s = ((c0 & 3) ^ ((r0 >> 1) & 3)) << 3;
  const int k1s = ((c1 & 3) ^ ((r1 >> 1) & 3)) << 3;
  const size_t aoff0 = (size_t)min(row_base + r0, NSLOT - 1) * DM + k0s;
  const size_t aoff1 = (size_t)min(row_base + r1, NSLOT - 1) * DM + k1s;
  const size_t boff0 = (size_t)r0 * DM + k0s;
  const size_t boff1 = (size_t)r1 * DM + k1s;

#define STG1(buf, kk)                                                          \
  do {                                                                         \
    GLD16(Xg + aoff0 + (kk), &As[buf][c0 * 8]);                                \
    GLD16(Xg + aoff1 + (kk), &As[buf][c1 * 8]);                                \
    GLD16(Bw + boff0 + (kk), &Ws[buf][c0 * 8]);                                \
    GLD16(Bw + boff1 + (kk), &Ws[buf][c1 * 8]);                                \
    GLD16(Bv + boff0 + (kk), &Vs[buf][c0 * 8]);                                \
    GLD16(Bv + boff1 + (kk), &Vs[buf][c1 * 8]);                                \
  } while (0)

  f32x4 acc_a[4][4], acc_b[4][4];
  const f32x4 z4 = {0.f, 0.f, 0.f, 0.f};
#pragma unroll
  for (int i = 0; i < 4; i++)
#pragma unroll
    for (int j = 0; j < 4; j++) { acc_a[i][j] = z4; acc_b[i][j] = z4; }

  STG1(0, 0);
  __syncthreads();            // slab 0 landed

  const int NS = DM / 32;     // 32 slabs
  for (int s = 0; s < NS; s++) {
    const int cur = s & 1;
    bf16x8_t af[4], wf[4], vf[4];
#pragma unroll
    for (int mi = 0; mi < 4; mi++) {
      const int row = wm + mi * 16 + lr;
      af[mi] = *(const bf16x8_t*)&As[cur][(row * 32 + kq) ^ (((row >> 1) & 3) << 3)];
    }
#pragma unroll
    for (int ni = 0; ni < 4; ni++) {
      const int row = wn + ni * 16 + lr;
      const int idx = (row * 32 + kq) ^ (((row >> 1) & 3) << 3);
      wf[ni] = *(const bf16x8_t*)&Ws[cur][idx];
      vf[ni] = *(const bf16x8_t*)&Vs[cur][idx];
    }
    if (s + 1 < NS) STG1(cur ^ 1, (s + 1) * 32);
#pragma unroll
    for (int mi = 0; mi < 4; mi++)
#pragma unroll
      for (int ni = 0; ni < 4; ni++) {
        acc_a[mi][ni] = __builtin_amdgcn_mfma_f32_16x16x32_bf16(af[mi], wf[ni], acc_a[mi][ni], 0, 0, 0);
        acc_b[mi][ni] = __builtin_amdgcn_mfma_f32_16x16x32_bf16(af[mi], vf[ni], acc_b[mi][ni], 0, 0, 0);
      }
    __syncthreads();
  }
#undef STG1

  const int q4 = (l >> 4) * 4;
#pragma unroll
  for (int mi = 0; mi < 4; mi++) {
#pragma unroll
    for (int r = 0; r < 4; r++) {
      const int mloc = mt * 128 + wm + mi * 16 + q4 + r;
      if (mloc >= cnt) continue;
      unsigned short* grow = G + (size_t)(off + mloc) * DH;
#pragma unroll
      for (int ni = 0; ni < 4; ni++) {
        const int h = h0 + wn + ni * 16 + lr;
        const float a = acc_a[mi][ni][r];
        const float b = acc_b[mi][ni][r];
        const float sgl = b / (1.0f + __expf(-b));  // silu(b)
        grow[h] = f2bf(a * sgl);
      }
    }
  }
}

// ---------------------------------------------------------------------------
// GEMM2 — full-K (split-K removed: ~512 active blocks = 2/CU is enough
// parallelism; halves Y write + combine read traffic). 128x128 tile,
// 2-phase dbuf, BK=32, swizzled.
// ---------------------------------------------------------------------------
__global__ __launch_bounds__(256, 2) void k_gemm2(
    const unsigned short* __restrict__ G, const unsigned short* __restrict__ B2t,
    unsigned short* __restrict__ Y, const int* __restrict__ counts) {
  const int e = blockIdx.z;
  int cnt;
  const int off = expert_off(counts, e, &cnt);
  const int mt = blockIdx.y;
  if (mt * 128 >= cnt) return;
  const int n0 = blockIdx.x * 128;
  const int row_base = off + mt * 128;

  __shared__ unsigned short As[2][128 * 32];
  __shared__ unsigned short Bs[2][128 * 32];   // 32 KB total

  const int t = threadIdx.x;
  const int l = t & 63;
  const int w = t >> 6;
  const int wm = (w >> 1) * 64;
  const int wn = (w & 1) * 64;
  const int lr = l & 15;
  const int kq = (l >> 4) * 8;

  const unsigned short* Bp = B2t + ((size_t)e * DM + n0) * DH;

  const int c0 = t, c1 = t + 256;
  const int r0 = c0 >> 2, r1 = c1 >> 2;
  const int k0s = ((c0 & 3) ^ ((r0 >> 1) & 3)) << 3;
  const int k1s = ((c1 & 3) ^ ((r1 >> 1) & 3)) << 3;
  const size_t aoff0 = (size_t)min(row_base + r0, NSLOT - 1) * DH + k0s;
  const size_t aoff1 = (size_t)min(row_base + r1, NSLOT - 1) * DH + k1s;
  const size_t boff0 = (size_t)r0 * DH + k0s;
  const size_t boff1 = (size_t)r1 * DH + k1s;

#define STG2(buf, kk)                                                          \
  do {                                                                         \
    GLD16(G + aoff0 + (kk), &As[buf][c0 * 8]);                                 \
    GLD16(G + aoff1 + (kk), &As[buf][c1 * 8]);                                 \
    GLD16(Bp + boff0 + (kk), &Bs[buf][c0 * 8]);                                \
    GLD16(Bp + boff1 + (kk), &Bs[buf][c1 * 8]);                                \
  } while (0)

  f32x4 acc[4][4];
  const f32x4 z4 = {0.f, 0.f, 0.f, 0.f};
#pragma unroll
  for (int i = 0; i < 4; i++)
#pragma unroll
    for (int j = 0; j < 4; j++) acc[i][j] = z4;

  STG2(0, 0);
  __syncthreads();

  const int NS = DH / 32;     // 64 slabs, full K
  for (int s = 0; s < NS; s++) {
    const int cur = s & 1;
    bf16x8_t af[4], bf[4];
#pragma unroll
    for (int mi = 0; mi < 4; mi++) {
      const int row = wm + mi * 16 + lr;
      af[mi] = *(const bf16x8_t*)&As[cur][(row * 32 + kq) ^ (((row >> 1) & 3) << 3)];
    }
#pragma unroll
    for (int ni = 0; ni < 4; ni++) {
      const int row = wn + ni * 16 + lr;
      bf[ni] = *(const bf16x8_t*)&Bs[cur][(row * 32 + kq) ^ (((row >> 1) & 3) << 3)];
    }
    if (s + 1 < NS) STG2(cur ^ 1, (s + 1) * 32);
#pragma unroll
    for (int mi = 0; mi < 4; mi++)
#pragma unroll
      for (int ni = 0; ni < 4; ni++)
        acc[mi][ni] = __builtin_amdgcn_mfma_f32_16x16x32_bf16(af[mi], bf[ni], acc[mi][ni], 0, 0, 0);
    __syncthreads();
  }
#undef STG2

  const int q4 = (l >> 4) * 4;
#pragma unroll
  for (int mi = 0; mi < 4; mi++) {
#pragma unroll
    for (int r = 0; r < 4; r++) {
      const int mloc = mt * 128 + wm + mi * 16 + q4 + r;
      if (mloc >= cnt) continue;
      unsigned short* yrow = Y + (size_t)(off + mloc) * DM;
#pragma unroll
      for (int ni = 0; ni < 4; ni++)
        yrow[n0 + wn + ni * 16 + lr] = f2bf(acc[mi][ni][r]);
    }
  }
}

// ---------------------------------------------------------------------------
// Combine: out[tok] = p0*Y[g0] + p1*Y[g1]; Y is bf16 (single copy, no split-K).
// ---------------------------------------------------------------------------
__global__ __launch_bounds__(256) void k_combine(
    const unsigned short* __restrict__ Y, const int* __restrict__ meta_e,
    const int* __restrict__ meta_idx, const float* __restrict__ meta_p,
    const int* __restrict__ counts, float* __restrict__ out) {
  const int tk = blockIdx.x;
  int offs[NE];
  { int s = 0;
#pragma unroll
    for (int e = 0; e < NE; e++) { offs[e] = s; s += counts[e]; } }
  const int s0 = tk * 2, s1 = s0 + 1;
  const int g0 = offs[meta_e[s0]] + meta_idx[s0];
  const int g1 = offs[meta_e[s1]] + meta_idx[s1];
  const float w0 = meta_p[s0], w1 = meta_p[s1];
  const ushort4 a0 = ((const ushort4*)(Y + (size_t)g0 * DM))[threadIdx.x];
  const ushort4 b0 = ((const ushort4*)(Y + (size_t)g1 * DM))[threadIdx.x];
  float4 o;
  o.x = w0 * bf2f(a0.x) + w1 * bf2f(b0.x);
  o.y = w0 * bf2f(a0.y) + w1 * bf2f(b0.y);
  o.z = w0 * bf2f(a0.z) + w1 * bf2f(b0.z);
  o.w = w0 * bf2f(a0.w) + w1 * bf2f(b0.w);
  ((float4*)(out + (size_t)tk * DM))[threadIdx.x] = o;
}

// ---------------------------------------------------------------------------
extern "C" void kernel_launch(void* const* d_in, const int* in_sizes, int n_in,
                              void* d_out, int out_size, void* d_ws, size_t ws_size,
                              hipStream_t stream) {
  const float* x    = (const float*)d_in[0];  // [2,2048,1024]
  const float* rw   = (const float*)d_in[1];  // [8,1024]
  const float* rb   = (const float*)d_in[2];  // [8]
  const float* W    = (const float*)d_in[3];  // [8,1024,2048]
  const float* V    = (const float*)d_in[4];  // [8,1024,2048]
  const float* Wout = (const float*)d_in[5];  // [8,2048,1024]
  float* out = (float*)d_out;

  // workspace carve-up (~145 MB); Y (bf16 [NSLOT][DM] = 16 MB) aliases
  // B1t (64 MB, dead after gemm1)
  char* p = (char*)d_ws;
  unsigned short* B1t = (unsigned short*)p; p += (size_t)NE * 4096 * DM * 2;   // 64 MB [e][n=4096][k=1024]
  unsigned short* Y   = (unsigned short*)B1t;                                  // alias: [NSLOT][DM] bf16
  unsigned short* B2t = (unsigned short*)p; p += (size_t)NE * DM * DH * 2;     // 32 MB [e][n=1024][k=2048]
  unsigned short* Xg  = (unsigned short*)p; p += (size_t)NSLOT * DM * 2;       // 16 MB
  unsigned short* G   = (unsigned short*)p; p += (size_t)NSLOT * DH * 2;       // 32 MB
  int*   counts      = (int*)p;   p += 256;
  int*   meta_e      = (int*)p;   p += (size_t)N_TOK * 2 * 4;
  int*   meta_idx    = (int*)p;   p += (size_t)N_TOK * 2 * 4;
  float* meta_p      = (float*)p; p += (size_t)N_TOK * 2 * 4;

  k_transpose<<<dim3(32, 8, 24), 256, 0, stream>>>(W, V, Wout, B1t, B2t, counts);
  k_router<<<N_TOK / RTR_TOK, 256, 0, stream>>>(x, rw, rb, counts, meta_e, meta_idx, meta_p);
  k_gather<<<N_TOK, 256, 0, stream>>>(x, meta_e, meta_idx, counts, Xg);
  k_gemm1<<<dim3(DH / 128, NSLOT / 128, NE), 256, 0, stream>>>(Xg, B1t, G, counts);
  k_gemm2<<<dim3(DM / 128, NSLOT / 128, NE), 256, 0, stream>>>(G, B2t, Y, counts);
  k_combine<<<N_TOK, 256, 0, stream>>>(Y, meta_e, meta_idx, meta_p, counts, out);
}